// Round 10
// baseline (471.950 us; speedup 1.0000x reference)
//
#include <hip/hip_runtime.h>
#include <cstdint>
#include <cstddef>

// SearchTransfer on MI355X (gfx950), fp32.
// B=4, C=64, H=W=64, L=4096, K=9C=576.
//
// Algebra:
//  - lr-patch norm is a positive per-column scalar -> cannot change argmax; dropped.
//  - S[a,b] = sum_{i,j} D[a+d, b+d], D = ref_flat^T * lr_flat (K=64).
//  - E-tile(r1,r2) = x-band of D-tile (register shuffles, R3-validated).
//  - S-tile(y',y) = E(y'-1,y-1)+E(y',y)+E(y'+1,y+1): band v2 streams tile-diagonals
//    with a register ring, barrier-FREE (wave-local reduce + global atomicMax),
//    depth-2 prefetch. Only 8B argmax keys leave the S phase.
//
// R9 lesson: cached E writes stream at only ~1.56 TB/s (L2 write-allocate) but
// make band L3-fast (15us/batch); R8's nt writes hit 2.85 TB/s but band read
// HBM slowly (46us/batch, prefetch-0 + barrier vmcnt drains). This round:
// (1) band v2 removes all barriers (old band's __syncthreads forced vmcnt(0)
//     drains killing overlap) and prefetches 2 tiles ahead;
// (2) within-run A/B: chunk0 gemmE<nt>, chunk1 gemmE<cached> -> per-dispatch
//     rocprof decides the uniform policy next round.

#define BATCH 4
#define CCH 64
#define LPIX 4096
typedef unsigned long long u64;
typedef float f4 __attribute__((ext_vector_type(4)));

__device__ __forceinline__ u64 packKey(float v, int idx) {
    unsigned int bits = __float_as_uint(v);
    unsigned int m = (bits & 0x80000000u) ? ~bits : (bits | 0x80000000u);
    // low 32 = ~idx so that larger key == smaller index on equal value
    return ((u64)m << 32) | (unsigned int)(~(unsigned int)idx);
}

// ---- prep: refT[b][p][c] transpose + ssq[b][p] = sum_c ref^2 -------------
__global__ __launch_bounds__(256) void prep_kernel(const float* __restrict__ ref,
                                                   float* __restrict__ refT,
                                                   float* __restrict__ ssq) {
    __shared__ float s[64 * 65];
    __shared__ float part[256];
    int pt = blockIdx.x, b = blockIdx.y, tid = threadIdx.x;
    const float* rb = ref + ((size_t)b * CCH) * LPIX + pt * 64;
    for (int k = 0; k < 16; ++k) {
        int n = tid + 256 * k;           // n = c*64 + p
        int c = n >> 6, p = n & 63;
        s[c * 65 + p] = rb[(size_t)c * LPIX + p];
    }
    __syncthreads();
    {
        int p = tid & 63, g = tid >> 6;
        float acc = 0.f;
        for (int c = g * 16; c < g * 16 + 16; ++c) { float v = s[c * 65 + p]; acc += v * v; }
        part[g * 64 + p] = acc;
    }
    __syncthreads();
    if (tid < 64) {
        float v = part[tid] + part[64 + tid] + part[128 + tid] + part[192 + tid];
        ssq[b * LPIX + pt * 64 + tid] = v;
    }
    float* tb = refT + ((size_t)b * LPIX + pt * 64) * 64;
    for (int k = 0; k < 16; ++k) {
        int n = tid + 256 * k;           // n = p*64 + c
        int p = n >> 6, c = n & 63;
        tb[n] = s[c * 65 + p];
    }
}

// ---- inv[b][p] = 1 / max(sqrt(3x3 box of ssq), 1e-12) --------------------
__global__ __launch_bounds__(256) void invnorm_kernel(const float* __restrict__ ssq,
                                                      float* __restrict__ inv) {
    int t = blockIdx.x * 256 + threadIdx.x;      // over BATCH*LPIX
    int b = t >> 12, p = t & 4095;
    int y = p >> 6, x = p & 63;
    const float* sb = ssq + b * LPIX;
    float n2 = 0.f;
    for (int i = -1; i <= 1; ++i)
        for (int j = -1; j <= 1; ++j) {
            int yy = y + i, xx = x + j;
            if (yy >= 0 && yy < 64 && xx >= 0 && xx < 64) n2 += sb[yy * 64 + xx];
        }
    inv[t] = 1.0f / fmaxf(sqrtf(n2), 1e-12f);
}

// ---- GEMM + x-band epilogue: one wave per 64x64 E-tile (R3-validated) ----
// D[x'][x] = sum_c ref[c,r1,x']*lr[c,r2,x]; E[x'][x] = D[x'-1][x-1]+D[x'][x]+D[x'+1][x+1]
template <bool NT>
__global__ __launch_bounds__(256, 2) void gemmE_kernel(const float* __restrict__ ref,
                                                       const float* __restrict__ lr,
                                                       float* __restrict__ E) {
    __shared__ __align__(16) float As[2 * 4096];   // [h][c][m], m = x' of tile r1=2by+h
    __shared__ __align__(16) float Bs[2 * 4096];   // [h][c][x], tile r2=2bx+h
    int bx = blockIdx.x, by = blockIdx.y, b = blockIdx.z, tid = threadIdx.x;
    const float* Ab = ref + (size_t)b * CCH * LPIX;
    const float* Bb = lr + (size_t)b * CCH * LPIX;
#pragma unroll
    for (int kk = 0; kk < 8; ++kk) {
        int n = tid + 256 * kk;          // 2048 f4: h = n>>10, c = (n>>4)&63, q = n&15
        int h = n >> 10, c = (n >> 4) & 63, q = n & 15;
        *(float4*)&As[h * 4096 + c * 64 + 4 * q] =
            *(const float4*)&Ab[(size_t)c * LPIX + (2 * by + h) * 64 + 4 * q];
        *(float4*)&Bs[h * 4096 + c * 64 + 4 * q] =
            *(const float4*)&Bb[(size_t)c * LPIX + (2 * bx + h) * 64 + 4 * q];
    }
    __syncthreads();
    int w = tid >> 6, lane = tid & 63, rg = lane >> 3, cg = lane & 7;
    const float* Ap = As + (w >> 1) * 4096 + rg * 8;
    const float* Bp = Bs + (w & 1) * 4096 + cg * 8;
    float acc[8][8] = {};
#pragma unroll 4
    for (int k = 0; k < 64; ++k) {
        float4 a0 = *(const float4*)(Ap + k * 64);
        float4 a1 = *(const float4*)(Ap + k * 64 + 4);
        float4 b0 = *(const float4*)(Bp + k * 64);
        float4 b1 = *(const float4*)(Bp + k * 64 + 4);
        float av[8] = {a0.x, a0.y, a0.z, a0.w, a1.x, a1.y, a1.z, a1.w};
        float bv[8] = {b0.x, b0.y, b0.z, b0.w, b1.x, b1.y, b1.z, b1.w};
#pragma unroll
        for (int i = 0; i < 8; ++i)
#pragma unroll
            for (int j = 0; j < 8; ++j) acc[i][j] = fmaf(av[i], bv[j], acc[i][j]);
    }
    // x-band epilogue in registers: E[r][c] = D[r-1][c-1] + D[r][c] + D[r+1][c+1]
    float up[7], lf[7], dn[8], rt[8], um, dpc;
#pragma unroll
    for (int t = 0; t < 7; ++t) up[t] = __shfl(acc[7][t], lane - 8, 64);
    um = __shfl(acc[7][7], lane - 9, 64);
#pragma unroll
    for (int t = 0; t < 7; ++t) lf[t] = __shfl(acc[t][7], lane - 1, 64);
#pragma unroll
    for (int t = 1; t < 8; ++t) dn[t] = __shfl(acc[0][t], lane + 8, 64);
    dpc = __shfl(acc[0][0], lane + 9, 64);
#pragma unroll
    for (int t = 1; t < 8; ++t) rt[t] = __shfl(acc[t][0], lane + 1, 64);

    int r1 = 2 * by + (w >> 1), r2 = 2 * bx + (w & 1);
    float* Et = E + ((size_t)b << 24) + ((size_t)((r1 << 6) + r2) << 12) + (rg * 8) * 64 + cg * 8;
    bool rgt = rg > 0, rlt = rg < 7, cgt = cg > 0, clt = cg < 7;
#pragma unroll
    for (int i = 0; i < 8; ++i) {
        float e[8];
#pragma unroll
        for (int j = 0; j < 8; ++j) {
            float dm, dpv;
            if (i >= 1) dm = (j >= 1) ? acc[i - 1][j - 1] : (cgt ? lf[i - 1] : 0.f);
            else        dm = rgt ? ((j >= 1) ? up[j - 1] : (cgt ? um : 0.f)) : 0.f;
            if (i <= 6) dpv = (j <= 6) ? acc[i + 1][j + 1] : (clt ? rt[i + 1] : 0.f);
            else        dpv = rlt ? ((j <= 6) ? dn[j + 1] : (clt ? dpc : 0.f)) : 0.f;
            e[j] = dm + acc[i][j] + dpv;
        }
        if (NT) {
            f4 o0 = {e[0], e[1], e[2], e[3]};
            f4 o1 = {e[4], e[5], e[6], e[7]};
            __builtin_nontemporal_store(o0, (f4*)(Et + i * 64));
            __builtin_nontemporal_store(o1, (f4*)(Et + i * 64 + 4));
        } else {
            *(float4*)(Et + i * 64)     = make_float4(e[0], e[1], e[2], e[3]);
            *(float4*)(Et + i * 64 + 4) = make_float4(e[4], e[5], e[6], e[7]);
        }
    }
}

// ---- band v2: barrier-free diagonal sweep, depth-2 prefetch ring ---------
// block (bx=segment, by=k+63, bz=batch-in-chunk); wave w owns x' rows 16w..16w+15.
// Lane l, iter i: f4 index 256w+64i+l -> x' = 16w+4i+(l>>4), cols 4*(l&15)..+3.
// Column max: in-register over i, then shfl_xor over lane bits 16/32, then
// global atomicMax per (y, x). Same key set as v1 -> bit-identical result.
__global__ __launch_bounds__(256) void band_kernel(const float* __restrict__ E,
                                                   const float* __restrict__ inv,
                                                   u64* __restrict__ packed) {
    int b = blockIdx.z;
    int k = (int)blockIdx.y - 63;
    int t_lo = k < 0 ? -k : 0;
    int t_hi = 64 - (k > 0 ? k : 0);
    int y0 = t_lo + (int)blockIdx.x * 16;
    if (y0 >= t_hi) return;
    int y1 = y0 + 16 < t_hi ? y0 + 16 : t_hi;
    const float* Ebase = E + ((size_t)b << 24);
    const float* invb = inv + b * LPIX;
    u64* pkb = packed + (size_t)b * LPIX;
    int tid = threadIdx.x;
    int w = tid >> 6, l = tid & 63;
    int lg = l >> 4, xq = l & 15;

    float4 Ea[4], Eb[4], Ec[4], P0[4], P1[4];
    auto LOADT = [&](float4* T, int t) {
        if (t >= t_lo && t < t_hi) {
            const float4* tp = (const float4*)(Ebase + ((size_t)(((t + k) << 6) + t) << 12));
#pragma unroll
            for (int i = 0; i < 4; ++i) T[i] = tp[(w << 8) + (i << 6) + l];
        } else {
#pragma unroll
            for (int i = 0; i < 4; ++i) T[i] = make_float4(0.f, 0.f, 0.f, 0.f);
        }
    };
    LOADT(Ea, y0 - 1); LOADT(Eb, y0); LOADT(Ec, y0 + 1);
    LOADT(P0, y0 + 2); LOADT(P1, y0 + 3);

    for (int y = y0; y < y1; ++y) {
        int yprow = (y + k) << 6;        // y' * 64
        u64 key[4] = {0, 0, 0, 0};
#pragma unroll
        for (int i = 0; i < 4; ++i) {
            int xp = (w << 4) + (i << 2) + lg;       // x'
            float iv = invb[yprow + xp];
            int idx = yprow + xp;
            float vx = (Ea[i].x + Eb[i].x + Ec[i].x) * iv;
            float vy = (Ea[i].y + Eb[i].y + Ec[i].y) * iv;
            float vz = (Ea[i].z + Eb[i].z + Ec[i].z) * iv;
            float vw = (Ea[i].w + Eb[i].w + Ec[i].w) * iv;
            u64 t0 = packKey(vx, idx); key[0] = key[0] > t0 ? key[0] : t0;
            u64 t1 = packKey(vy, idx); key[1] = key[1] > t1 ? key[1] : t1;
            u64 t2 = packKey(vz, idx); key[2] = key[2] > t2 ? key[2] : t2;
            u64 t3 = packKey(vw, idx); key[3] = key[3] > t3 ? key[3] : t3;
        }
        // reduce over the lg dimension (16 x' rows per wave): xor 16, then 32
#pragma unroll
        for (int d = 16; d <= 32; d <<= 1)
#pragma unroll
            for (int j = 0; j < 4; ++j) {
                u64 o = __shfl_xor(key[j], d, 64);
                key[j] = key[j] > o ? key[j] : o;
            }
        if (lg == 0) {                   // lanes 0..15: one per column quad
            int cb = (y << 6) + (xq << 2);
#pragma unroll
            for (int j = 0; j < 4; ++j) atomicMax(&pkb[cb + j], key[j]);
        }
        if (y + 1 < y1) {
#pragma unroll
            for (int i = 0; i < 4; ++i) {
                Ea[i] = Eb[i]; Eb[i] = Ec[i]; Ec[i] = P0[i]; P0[i] = P1[i];
            }
            LOADT(P1, y + 4);            // issued 2 steps before use
        }
    }
}

// ---- gather + fold: one wave per output pixel ----------------------------
__global__ __launch_bounds__(256) void gather_kernel(const u64* __restrict__ packed,
                                                     const float* __restrict__ refT,
                                                     float* __restrict__ Tt) {
    int b = blockIdx.y;
    int wave = threadIdx.x >> 6, lane = threadIdx.x & 63;
    int p = blockIdx.x * 4 + wave;       // 0..4095
    int py = p >> 6, px = p & 63;
    const u64* pk = packed + (size_t)b * LPIX;
    const float* rT = refT + (size_t)b * LPIX * 64;
    float acc = 0.f;
#pragma unroll
    for (int i = 0; i < 3; ++i)
#pragma unroll
        for (int j = 0; j < 3; ++j) {
            int qy = py + 1 - i, qx = px + 1 - j;
            if ((unsigned)qy >= 64u || (unsigned)qx >= 64u) continue;
            int aidx = (int)(~(unsigned int)pk[qy * 64 + qx]);
            int ry = (aidx >> 6) + i - 1, rx = (aidx & 63) + j - 1;
            if ((unsigned)ry >= 64u || (unsigned)rx >= 64u) continue;
            acc += rT[(size_t)(ry * 64 + rx) * 64 + lane];
        }
    Tt[((size_t)b * LPIX + p) * 64 + lane] = acc;
}

// ---- 1x1 conv: z[b][co][p] = w1[co][0:64]*lr + w1[co][64:128]*T + b1 -----
#define XST 36
__global__ __launch_bounds__(256) void conv1_kernel(const float* __restrict__ lr,
                                                    const float* __restrict__ Tt,
                                                    const float* __restrict__ w1,
                                                    const float* __restrict__ b1,
                                                    float* __restrict__ z) {
    __shared__ __align__(16) float xs[128 * XST];
    __shared__ __align__(16) float wsm[64 * 128];
    int pt = blockIdx.x, b = blockIdx.y, tid = threadIdx.x;
    for (int k = 0; k < 8; ++k) {
        int n = tid + 256 * k;           // 2048 float4s of w1
        *(float4*)&wsm[4 * n] = *(const float4*)&w1[4 * n];
    }
    const float* lrb = lr + (size_t)b * CCH * LPIX + pt * 32;
    for (int k = 0; k < 2; ++k) {
        int n = tid + 256 * k;           // 512 f4: c = n>>3, q = n&7
        int c = n >> 3, q = n & 7;
        *(float4*)&xs[c * XST + 4 * q] = *(const float4*)&lrb[(size_t)c * LPIX + 4 * q];
    }
    const float* Tb = Tt + ((size_t)b * LPIX + pt * 32) * 64;
    for (int k = 0; k < 2; ++k) {
        int n = tid + 256 * k;           // 512 f4: p = n>>4, cq = n&15
        int p = n >> 4, cq = n & 15;
        float4 v = *(const float4*)&Tb[p * 64 + 4 * cq];
        xs[(64 + 4 * cq + 0) * XST + p] = v.x;
        xs[(64 + 4 * cq + 1) * XST + p] = v.y;
        xs[(64 + 4 * cq + 2) * XST + p] = v.z;
        xs[(64 + 4 * cq + 3) * XST + p] = v.w;
    }
    __syncthreads();
    int p = tid & 31, g = tid >> 5;      // g: 8 groups of 8 output channels
    float acc[8];
#pragma unroll
    for (int t = 0; t < 8; ++t) acc[t] = b1[g * 8 + t];
    for (int c = 0; c < 128; ++c) {
        float xv = xs[c * XST + p];
#pragma unroll
        for (int t = 0; t < 8; ++t) acc[t] = fmaf(wsm[(g * 8 + t) * 128 + c], xv, acc[t]);
    }
    float* zb = z + (size_t)b * CCH * LPIX + pt * 32;
#pragma unroll
    for (int t = 0; t < 8; ++t) zb[(size_t)(g * 8 + t) * LPIX + p] = acc[t];
}

// ---- depthwise 3x3 + bias + relu -> out ----------------------------------
__global__ __launch_bounds__(256) void dw_kernel(const float* __restrict__ z,
                                                 const float* __restrict__ wd,
                                                 const float* __restrict__ bd,
                                                 float* __restrict__ out) {
    __shared__ __align__(16) float zs[4096];
    int c = blockIdx.x, b = blockIdx.y, tid = threadIdx.x;
    const float* zb = z + ((size_t)b * CCH + c) * LPIX;
    for (int k = 0; k < 4; ++k) {
        int n = tid + 256 * k;
        *(float4*)&zs[4 * n] = *(const float4*)&zb[4 * n];
    }
    __syncthreads();
    float w[9];
#pragma unroll
    for (int t = 0; t < 9; ++t) w[t] = wd[c * 9 + t];
    float bias = bd[c];
    float* ob = out + ((size_t)b * CCH + c) * LPIX;
    for (int s = 0; s < 16; ++s) {
        int p = tid + 256 * s;
        int y = p >> 6, x = p & 63;
        float acc = bias;
#pragma unroll
        for (int i = 0; i < 3; ++i) {
            int yy = y + i - 1;
            if ((unsigned)yy >= 64u) continue;
#pragma unroll
            for (int j = 0; j < 3; ++j) {
                int xx = x + j - 1;
                if ((unsigned)xx >= 64u) continue;
                acc = fmaf(zs[yy * 64 + xx], w[i * 3 + j], acc);
            }
        }
        ob[p] = fmaxf(acc, 0.f);
    }
}

extern "C" void kernel_launch(void* const* d_in, const int* in_sizes, int n_in,
                              void* d_out, int out_size, void* d_ws, size_t ws_size,
                              hipStream_t stream) {
    const float* lr  = (const float*)d_in[0];
    const float* ref = (const float*)d_in[1];
    const float* w1  = (const float*)d_in[2];
    const float* b1  = (const float*)d_in[3];
    const float* wd  = (const float*)d_in[4];
    const float* bd  = (const float*)d_in[5];
    float* out = (float*)d_out;

    float* ws = (float*)d_ws;
    float* refT = ws;                                   // 1,048,576 f
    float* ssq  = refT + (size_t)1048576;               //    16,384 f
    float* inv  = ssq + 16384;                          //    16,384 f
    u64* packed = (u64*)(inv + 16384);                  //    16,384 u64
    float* Tt = (float*)(packed + 16384);               // 1,048,576 f
    float* z  = Tt + (size_t)1048576;                   // 1,048,576 f
    float* E  = z + (size_t)1048576;                    // NB * 16,777,216 f (reused)

    const size_t base = 12845056ull;                    // bytes before E
    const size_t per  = 67108864ull;                    // E bytes per batch
    int NB = (ws_size >= base + 2 * per) ? 2 : 1;

    hipMemsetAsync(packed, 0, (size_t)BATCH * LPIX * sizeof(u64), stream);
    prep_kernel<<<dim3(64, BATCH), 256, 0, stream>>>(ref, refT, ssq);
    invnorm_kernel<<<dim3(64), 256, 0, stream>>>(ssq, inv);
    if (NB == 2) {
        // A/B within one run: chunk0 = nontemporal stores, chunk1 = cached stores.
        gemmE_kernel<true><<<dim3(32, 32, 2), 256, 0, stream>>>(ref, lr, E);
        band_kernel<<<dim3(4, 127, 2), 256, 0, stream>>>(E, inv, packed);
        gemmE_kernel<false><<<dim3(32, 32, 2), 256, 0, stream>>>(
            ref + (size_t)2 * CCH * LPIX, lr + (size_t)2 * CCH * LPIX, E);
        band_kernel<<<dim3(4, 127, 2), 256, 0, stream>>>(
            E, inv + (size_t)2 * LPIX, packed + (size_t)2 * LPIX);
    } else {
        for (int b0 = 0; b0 < BATCH; ++b0) {
            gemmE_kernel<false><<<dim3(32, 32, 1), 256, 0, stream>>>(
                ref + (size_t)b0 * CCH * LPIX, lr + (size_t)b0 * CCH * LPIX, E);
            band_kernel<<<dim3(4, 127, 1), 256, 0, stream>>>(
                E, inv + (size_t)b0 * LPIX, packed + (size_t)b0 * LPIX);
        }
    }
    gather_kernel<<<dim3(1024, BATCH), 256, 0, stream>>>(packed, refT, Tt);
    conv1_kernel<<<dim3(128, BATCH), 256, 0, stream>>>(lr, Tt, w1, b1, z);
    dw_kernel<<<dim3(64, BATCH), 256, 0, stream>>>(z, wd, bd, out);
}

// Round 11
// 274.661 us; speedup vs baseline: 1.7183x; 1.7183x over previous
//
#include <hip/hip_runtime.h>
#include <cstdint>
#include <cstddef>

// SearchTransfer on MI355X (gfx950), fp32.
// B=4, C=64, H=W=64, L=4096, K=9C=576.
//
// Algebra:
//  - lr-patch norm is a positive per-column scalar -> cannot change argmax; dropped.
//  - S[a,b] = sum_{i,j} D[a+d, b+d], D = ref_flat^T * lr_flat (K=64).
//  - E-tile(r1,r2) = x-band of D-tile (register shuffles, R3-validated).
//  - S-tile(y',y) = E(y'-1,y-1)+E(y',y)+E(y'+1,y+1): band v1 (R2/R9-validated).
//
// R10 lesson: band v2's 5-tile register ring spilled (VGPR=60 granted vs 80+
// needed; 64 MiB scratch writes/dispatch) -> revert to R9's validated band v1.
// R9 analysis: gemmE is WRITE-bound (128 MiB cached E stream at 1.63 TB/s,
// 2 blocks/CU) with 9.4M LDS bank conflicts from 8-way-conflicting staging
// writes. gemmE v2: K-split staging (32ch/stage, single buffer + register
// prefetch under FMA) -> ~35 KiB LDS -> 3-4 blocks/CU for write concurrency;
// stride-68 padding kills the write conflicts. Same channel order + epilogue
// -> bit-identical output.

#define BATCH 4
#define CCH 64
#define LPIX 4096
typedef unsigned long long u64;

__device__ __forceinline__ u64 packKey(float v, int idx) {
    unsigned int bits = __float_as_uint(v);
    unsigned int m = (bits & 0x80000000u) ? ~bits : (bits | 0x80000000u);
    // low 32 = ~idx so that larger key == smaller index on equal value
    return ((u64)m << 32) | (unsigned int)(~(unsigned int)idx);
}

// ---- prep: refT[b][p][c] transpose + ssq[b][p] = sum_c ref^2 -------------
__global__ __launch_bounds__(256) void prep_kernel(const float* __restrict__ ref,
                                                   float* __restrict__ refT,
                                                   float* __restrict__ ssq) {
    __shared__ float s[64 * 65];
    __shared__ float part[256];
    int pt = blockIdx.x, b = blockIdx.y, tid = threadIdx.x;
    const float* rb = ref + ((size_t)b * CCH) * LPIX + pt * 64;
    for (int k = 0; k < 16; ++k) {
        int n = tid + 256 * k;           // n = c*64 + p
        int c = n >> 6, p = n & 63;
        s[c * 65 + p] = rb[(size_t)c * LPIX + p];
    }
    __syncthreads();
    {
        int p = tid & 63, g = tid >> 6;
        float acc = 0.f;
        for (int c = g * 16; c < g * 16 + 16; ++c) { float v = s[c * 65 + p]; acc += v * v; }
        part[g * 64 + p] = acc;
    }
    __syncthreads();
    if (tid < 64) {
        float v = part[tid] + part[64 + tid] + part[128 + tid] + part[192 + tid];
        ssq[b * LPIX + pt * 64 + tid] = v;
    }
    float* tb = refT + ((size_t)b * LPIX + pt * 64) * 64;
    for (int k = 0; k < 16; ++k) {
        int n = tid + 256 * k;           // n = p*64 + c
        int p = n >> 6, c = n & 63;
        tb[n] = s[c * 65 + p];
    }
}

// ---- inv[b][p] = 1 / max(sqrt(3x3 box of ssq), 1e-12) --------------------
__global__ __launch_bounds__(256) void invnorm_kernel(const float* __restrict__ ssq,
                                                      float* __restrict__ inv) {
    int t = blockIdx.x * 256 + threadIdx.x;      // over BATCH*LPIX
    int b = t >> 12, p = t & 4095;
    int y = p >> 6, x = p & 63;
    const float* sb = ssq + b * LPIX;
    float n2 = 0.f;
    for (int i = -1; i <= 1; ++i)
        for (int j = -1; j <= 1; ++j) {
            int yy = y + i, xx = x + j;
            if (yy >= 0 && yy < 64 && xx >= 0 && xx < 64) n2 += sb[yy * 64 + xx];
        }
    inv[t] = 1.0f / fmaxf(sqrtf(n2), 1e-12f);
}

// ---- GEMM + x-band epilogue: one wave per 64x64 E-tile (v2) --------------
// D[x'][x] = sum_c ref[c,r1,x']*lr[c,r2,x]; E[x'][x] = D[x'-1][x-1]+D[x'][x]+D[x'+1][x+1]
// K-split staging: 32 channels in LDS at a time ([h][c:32][m:64 pad 68], ~35 KiB
// total), second half register-prefetched under the first half's FMA loop.
__global__ __launch_bounds__(256, 3) void gemmE_kernel(const float* __restrict__ ref,
                                                       const float* __restrict__ lr,
                                                       float* __restrict__ E) {
    __shared__ __align__(16) float As[2 * 32 * 68];   // 17408 B
    __shared__ __align__(16) float Bs[2 * 32 * 68];   // 17408 B
    int bx = blockIdx.x, by = blockIdx.y, b = blockIdx.z, tid = threadIdx.x;
    const float* Ab = ref + (size_t)b * CCH * LPIX;
    const float* Bb = lr + (size_t)b * CCH * LPIX;

    float4 pa[4], pb[4];
#pragma unroll
    for (int it = 0; it < 4; ++it) {     // stage channels 0..31 into regs
        int n = tid + 256 * it;          // h = n>>9, c = (n>>4)&31, q = n&15
        int h = n >> 9, c = (n >> 4) & 31, q = n & 15;
        pa[it] = *(const float4*)&Ab[(size_t)c * LPIX + (2 * by + h) * 64 + 4 * q];
        pb[it] = *(const float4*)&Bb[(size_t)c * LPIX + (2 * bx + h) * 64 + 4 * q];
    }

    int w = tid >> 6, lane = tid & 63, rg = lane >> 3, cg = lane & 7;
    const float* Ap = As + (w >> 1) * 2176 + rg * 8;
    const float* Bp = Bs + (w & 1) * 2176 + cg * 8;
    float acc[8][8] = {};

#pragma unroll
    for (int kh = 0; kh < 2; ++kh) {
        // commit staged regs to LDS (pad-68: ~2-way write conflicts, free)
#pragma unroll
        for (int it = 0; it < 4; ++it) {
            int n = tid + 256 * it;
            int h = n >> 9, c = (n >> 4) & 31, q = n & 15;
            *(float4*)&As[h * 2176 + c * 68 + 4 * q] = pa[it];
            *(float4*)&Bs[h * 2176 + c * 68 + 4 * q] = pb[it];
        }
        __syncthreads();
        if (kh == 0) {                   // prefetch channels 32..63 under FMA
#pragma unroll
            for (int it = 0; it < 4; ++it) {
                int n = tid + 256 * it;
                int h = n >> 9, c = ((n >> 4) & 31) + 32, q = n & 15;
                pa[it] = *(const float4*)&Ab[(size_t)c * LPIX + (2 * by + h) * 64 + 4 * q];
                pb[it] = *(const float4*)&Bb[(size_t)c * LPIX + (2 * bx + h) * 64 + 4 * q];
            }
        }
#pragma unroll 4
        for (int kk = 0; kk < 32; ++kk) {
            float4 a0 = *(const float4*)(Ap + kk * 68);
            float4 a1 = *(const float4*)(Ap + kk * 68 + 4);
            float4 b0 = *(const float4*)(Bp + kk * 68);
            float4 b1 = *(const float4*)(Bp + kk * 68 + 4);
            float av[8] = {a0.x, a0.y, a0.z, a0.w, a1.x, a1.y, a1.z, a1.w};
            float bv[8] = {b0.x, b0.y, b0.z, b0.w, b1.x, b1.y, b1.z, b1.w};
#pragma unroll
            for (int i = 0; i < 8; ++i)
#pragma unroll
                for (int j = 0; j < 8; ++j) acc[i][j] = fmaf(av[i], bv[j], acc[i][j]);
        }
        if (kh == 0) __syncthreads();    // WAR before overwriting LDS
    }

    // x-band epilogue in registers: E[r][c] = D[r-1][c-1] + D[r][c] + D[r+1][c+1]
    float up[7], lf[7], dn[8], rt[8], um, dpc;
#pragma unroll
    for (int t = 0; t < 7; ++t) up[t] = __shfl(acc[7][t], lane - 8, 64);
    um = __shfl(acc[7][7], lane - 9, 64);
#pragma unroll
    for (int t = 0; t < 7; ++t) lf[t] = __shfl(acc[t][7], lane - 1, 64);
#pragma unroll
    for (int t = 1; t < 8; ++t) dn[t] = __shfl(acc[0][t], lane + 8, 64);
    dpc = __shfl(acc[0][0], lane + 9, 64);
#pragma unroll
    for (int t = 1; t < 8; ++t) rt[t] = __shfl(acc[t][0], lane + 1, 64);

    int r1 = 2 * by + (w >> 1), r2 = 2 * bx + (w & 1);
    float* Et = E + ((size_t)b << 24) + ((size_t)((r1 << 6) + r2) << 12) + (rg * 8) * 64 + cg * 8;
    bool rgt = rg > 0, rlt = rg < 7, cgt = cg > 0, clt = cg < 7;
#pragma unroll
    for (int i = 0; i < 8; ++i) {
        float e[8];
#pragma unroll
        for (int j = 0; j < 8; ++j) {
            float dm, dpv;
            if (i >= 1) dm = (j >= 1) ? acc[i - 1][j - 1] : (cgt ? lf[i - 1] : 0.f);
            else        dm = rgt ? ((j >= 1) ? up[j - 1] : (cgt ? um : 0.f)) : 0.f;
            if (i <= 6) dpv = (j <= 6) ? acc[i + 1][j + 1] : (clt ? rt[i + 1] : 0.f);
            else        dpv = rlt ? ((j <= 6) ? dn[j + 1] : (clt ? dpc : 0.f)) : 0.f;
            e[j] = dm + acc[i][j] + dpv;
        }
        *(float4*)(Et + i * 64)     = make_float4(e[0], e[1], e[2], e[3]);
        *(float4*)(Et + i * 64 + 4) = make_float4(e[4], e[5], e[6], e[7]);
    }
}

// ---- band v1: diagonal-segment sweep, register ring of 3 E-tiles (R9) ----
// block (bx=segment, by=k+63, bz=batch); S-tile(y+k, y) = Ea+Eb+Ec elementwise
__global__ __launch_bounds__(256) void band_kernel(const float* __restrict__ E,
                                                   const float* __restrict__ inv,
                                                   u64* __restrict__ packed) {
    __shared__ u64 red[16 * 65];
    int b = blockIdx.z;
    int k = (int)blockIdx.y - 63;
    int t_lo = k < 0 ? -k : 0;
    int t_hi = 64 - (k > 0 ? k : 0);
    int y0 = t_lo + (int)blockIdx.x * 16;
    if (y0 >= t_hi) return;
    int y1 = y0 + 16 < t_hi ? y0 + 16 : t_hi;
    const float* Ebase = E + ((size_t)b << 24);
    const float* invb = inv + b * LPIX;
    u64* pkb = packed + (size_t)b * LPIX;
    int tid = threadIdx.x;
    int c4 = tid & 15, s = tid >> 4;     // cols 4*c4.., x' strata s+16i

    float4 Ea[4], Eb[4], Ec[4];
    auto LOADT = [&](float4* T, int t) {
        if (t >= t_lo && t < t_hi) {
            const float4* tp = (const float4*)(Ebase + ((size_t)(((t + k) << 6) + t) << 12));
#pragma unroll
            for (int i = 0; i < 4; ++i) T[i] = tp[tid + 256 * i];
        } else {
#pragma unroll
            for (int i = 0; i < 4; ++i) T[i] = make_float4(0.f, 0.f, 0.f, 0.f);
        }
    };
    LOADT(Ea, y0 - 1); LOADT(Eb, y0); LOADT(Ec, y0 + 1);

    for (int y = y0; y < y1; ++y) {
        int yprow = (y + k) << 6;        // y' * 64
        u64 kc0 = 0, kc1 = 0, kc2 = 0, kc3 = 0;
#pragma unroll
        for (int i = 0; i < 4; ++i) {
            int xr = s + 16 * i;         // x'
            float iv = invb[yprow + xr];
            int idx = yprow + xr;        // p' = y'*64 + x'
            float vx = (Ea[i].x + Eb[i].x + Ec[i].x) * iv;
            float vy = (Ea[i].y + Eb[i].y + Ec[i].y) * iv;
            float vz = (Ea[i].z + Eb[i].z + Ec[i].z) * iv;
            float vw = (Ea[i].w + Eb[i].w + Ec[i].w) * iv;
            u64 t0 = packKey(vx, idx); kc0 = kc0 > t0 ? kc0 : t0;
            u64 t1 = packKey(vy, idx); kc1 = kc1 > t1 ? kc1 : t1;
            u64 t2 = packKey(vz, idx); kc2 = kc2 > t2 ? kc2 : t2;
            u64 t3 = packKey(vw, idx); kc3 = kc3 > t3 ? kc3 : t3;
        }
        red[s * 65 + 4 * c4 + 0] = kc0;
        red[s * 65 + 4 * c4 + 1] = kc1;
        red[s * 65 + 4 * c4 + 2] = kc2;
        red[s * 65 + 4 * c4 + 3] = kc3;
        __syncthreads();
        if (tid < 64) {
            u64 m = red[tid];
#pragma unroll
            for (int ss = 1; ss < 16; ++ss) {
                u64 v = red[ss * 65 + tid];
                m = m > v ? m : v;
            }
            atomicMax(&pkb[(y << 6) + tid], m);
        }
        __syncthreads();
        if (y + 1 < y1) {
            float4 En[4];
            LOADT(En, y + 2);
#pragma unroll
            for (int i = 0; i < 4; ++i) { Ea[i] = Eb[i]; Eb[i] = Ec[i]; Ec[i] = En[i]; }
        }
    }
}

// ---- gather + fold: one wave per output pixel ----------------------------
__global__ __launch_bounds__(256) void gather_kernel(const u64* __restrict__ packed,
                                                     const float* __restrict__ refT,
                                                     float* __restrict__ Tt) {
    int b = blockIdx.y;
    int wave = threadIdx.x >> 6, lane = threadIdx.x & 63;
    int p = blockIdx.x * 4 + wave;       // 0..4095
    int py = p >> 6, px = p & 63;
    const u64* pk = packed + (size_t)b * LPIX;
    const float* rT = refT + (size_t)b * LPIX * 64;
    float acc = 0.f;
#pragma unroll
    for (int i = 0; i < 3; ++i)
#pragma unroll
        for (int j = 0; j < 3; ++j) {
            int qy = py + 1 - i, qx = px + 1 - j;
            if ((unsigned)qy >= 64u || (unsigned)qx >= 64u) continue;
            int aidx = (int)(~(unsigned int)pk[qy * 64 + qx]);
            int ry = (aidx >> 6) + i - 1, rx = (aidx & 63) + j - 1;
            if ((unsigned)ry >= 64u || (unsigned)rx >= 64u) continue;
            acc += rT[(size_t)(ry * 64 + rx) * 64 + lane];
        }
    Tt[((size_t)b * LPIX + p) * 64 + lane] = acc;
}

// ---- 1x1 conv: z[b][co][p] = w1[co][0:64]*lr + w1[co][64:128]*T + b1 -----
#define XST 36
__global__ __launch_bounds__(256) void conv1_kernel(const float* __restrict__ lr,
                                                    const float* __restrict__ Tt,
                                                    const float* __restrict__ w1,
                                                    const float* __restrict__ b1,
                                                    float* __restrict__ z) {
    __shared__ __align__(16) float xs[128 * XST];
    __shared__ __align__(16) float wsm[64 * 128];
    int pt = blockIdx.x, b = blockIdx.y, tid = threadIdx.x;
    for (int k = 0; k < 8; ++k) {
        int n = tid + 256 * k;           // 2048 float4s of w1
        *(float4*)&wsm[4 * n] = *(const float4*)&w1[4 * n];
    }
    const float* lrb = lr + (size_t)b * CCH * LPIX + pt * 32;
    for (int k = 0; k < 2; ++k) {
        int n = tid + 256 * k;           // 512 f4: c = n>>3, q = n&7
        int c = n >> 3, q = n & 7;
        *(float4*)&xs[c * XST + 4 * q] = *(const float4*)&lrb[(size_t)c * LPIX + 4 * q];
    }
    const float* Tb = Tt + ((size_t)b * LPIX + pt * 32) * 64;
    for (int k = 0; k < 2; ++k) {
        int n = tid + 256 * k;           // 512 f4: p = n>>4, cq = n&15
        int p = n >> 4, cq = n & 15;
        float4 v = *(const float4*)&Tb[p * 64 + 4 * cq];
        xs[(64 + 4 * cq + 0) * XST + p] = v.x;
        xs[(64 + 4 * cq + 1) * XST + p] = v.y;
        xs[(64 + 4 * cq + 2) * XST + p] = v.z;
        xs[(64 + 4 * cq + 3) * XST + p] = v.w;
    }
    __syncthreads();
    int p = tid & 31, g = tid >> 5;      // g: 8 groups of 8 output channels
    float acc[8];
#pragma unroll
    for (int t = 0; t < 8; ++t) acc[t] = b1[g * 8 + t];
    for (int c = 0; c < 128; ++c) {
        float xv = xs[c * XST + p];
#pragma unroll
        for (int t = 0; t < 8; ++t) acc[t] = fmaf(wsm[(g * 8 + t) * 128 + c], xv, acc[t]);
    }
    float* zb = z + (size_t)b * CCH * LPIX + pt * 32;
#pragma unroll
    for (int t = 0; t < 8; ++t) zb[(size_t)(g * 8 + t) * LPIX + p] = acc[t];
}

// ---- depthwise 3x3 + bias + relu -> out ----------------------------------
__global__ __launch_bounds__(256) void dw_kernel(const float* __restrict__ z,
                                                 const float* __restrict__ wd,
                                                 const float* __restrict__ bd,
                                                 float* __restrict__ out) {
    __shared__ __align__(16) float zs[4096];
    int c = blockIdx.x, b = blockIdx.y, tid = threadIdx.x;
    const float* zb = z + ((size_t)b * CCH + c) * LPIX;
    for (int k = 0; k < 4; ++k) {
        int n = tid + 256 * k;
        *(float4*)&zs[4 * n] = *(const float4*)&zb[4 * n];
    }
    __syncthreads();
    float w[9];
#pragma unroll
    for (int t = 0; t < 9; ++t) w[t] = wd[c * 9 + t];
    float bias = bd[c];
    float* ob = out + ((size_t)b * CCH + c) * LPIX;
    for (int s = 0; s < 16; ++s) {
        int p = tid + 256 * s;
        int y = p >> 6, x = p & 63;
        float acc = bias;
#pragma unroll
        for (int i = 0; i < 3; ++i) {
            int yy = y + i - 1;
            if ((unsigned)yy >= 64u) continue;
#pragma unroll
            for (int j = 0; j < 3; ++j) {
                int xx = x + j - 1;
                if ((unsigned)xx >= 64u) continue;
                acc = fmaf(zs[yy * 64 + xx], w[i * 3 + j], acc);
            }
        }
        ob[p] = fmaxf(acc, 0.f);
    }
}

extern "C" void kernel_launch(void* const* d_in, const int* in_sizes, int n_in,
                              void* d_out, int out_size, void* d_ws, size_t ws_size,
                              hipStream_t stream) {
    const float* lr  = (const float*)d_in[0];
    const float* ref = (const float*)d_in[1];
    const float* w1  = (const float*)d_in[2];
    const float* b1  = (const float*)d_in[3];
    const float* wd  = (const float*)d_in[4];
    const float* bd  = (const float*)d_in[5];
    float* out = (float*)d_out;

    float* ws = (float*)d_ws;
    float* refT = ws;                                   // 1,048,576 f
    float* ssq  = refT + (size_t)1048576;               //    16,384 f
    float* inv  = ssq + 16384;                          //    16,384 f
    u64* packed = (u64*)(inv + 16384);                  //    16,384 u64
    float* Tt = (float*)(packed + 16384);               // 1,048,576 f
    float* z  = Tt + (size_t)1048576;                   // 1,048,576 f
    float* E  = z + (size_t)1048576;                    // NB * 16,777,216 f (reused)

    const size_t base = 12845056ull;                    // bytes before E
    const size_t per  = 67108864ull;                    // E bytes per batch
    // NB=2 keeps live E at 128 MiB -> L3-resident for band reads (R9-validated).
    int NB = (ws_size >= base + 2 * per) ? 2 : 1;

    hipMemsetAsync(packed, 0, (size_t)BATCH * LPIX * sizeof(u64), stream);
    prep_kernel<<<dim3(64, BATCH), 256, 0, stream>>>(ref, refT, ssq);
    invnorm_kernel<<<dim3(64), 256, 0, stream>>>(ssq, inv);
    for (int b0 = 0; b0 < BATCH; b0 += NB) {
        gemmE_kernel<<<dim3(32, 32, NB), 256, 0, stream>>>(
            ref + (size_t)b0 * CCH * LPIX, lr + (size_t)b0 * CCH * LPIX, E);
        band_kernel<<<dim3(4, 127, NB), 256, 0, stream>>>(
            E, inv + (size_t)b0 * LPIX, packed + (size_t)b0 * LPIX);
    }
    gather_kernel<<<dim3(1024, BATCH), 256, 0, stream>>>(packed, refT, Tt);
    conv1_kernel<<<dim3(128, BATCH), 256, 0, stream>>>(lr, Tt, w1, b1, z);
    dw_kernel<<<dim3(64, BATCH), 256, 0, stream>>>(z, wd, bd, out);
}